// Round 1
// baseline (4980.042 us; speedup 1.0000x reference)
//
#include <hip/hip_runtime.h>
#include <cstdint>
#include <cstddef>

#define T_SZ 2048
#define NROW 65536  // B*T = 32*2048

typedef float f32x4 __attribute__((ext_vector_type(4)));
typedef short bf16x8 __attribute__((ext_vector_type(8)));

static __device__ __forceinline__ unsigned short f2bf(float f) {
  union { float f; unsigned u; } v; v.f = f;
  unsigned r = v.u + 0x7fffu + ((v.u >> 16) & 1u);   // RNE
  return (unsigned short)(r >> 16);
}
static __device__ __forceinline__ float bf2f(unsigned short h) {
  union { unsigned u; float f; } v; v.u = ((unsigned)h) << 16; return v.f;
}
static __device__ __forceinline__ float gelu_f(float x) {
  return 0.5f * x * (1.0f + erff(x * 0.70710678118654752440f));
}

// ------------------------------------------------------------------
// K0: convert + transpose weights to bf16 in ws.
// w1T[128][1024]  from lat_w1[0:1024][128]
// rw1T/sw1T/lw1T[128][128] (transposed), rw2T/sw2T[1024][128] (transposed)
// ------------------------------------------------------------------
__global__ __launch_bounds__(256) void kPrep(
    const float* __restrict__ lat_w1, const float* __restrict__ rw1,
    const float* __restrict__ rw2, const float* __restrict__ sw1,
    const float* __restrict__ sw2, const float* __restrict__ lw1,
    unsigned short* __restrict__ w1T, unsigned short* __restrict__ rw1T,
    unsigned short* __restrict__ rw2T, unsigned short* __restrict__ sw1T,
    unsigned short* __restrict__ sw2T, unsigned short* __restrict__ lw1T) {
  int i = blockIdx.x * 256 + threadIdx.x;
  if (i < 131072) {
    int j = i >> 10, k = i & 1023;                 // w1T[j][k] = w1[k][j]
    w1T[i] = f2bf(lat_w1[(size_t)k * 128 + j]);
    int n = i >> 7, k2 = i & 127;                  // w2T[n][k] = w2[k][n]
    rw2T[i] = f2bf(rw2[(size_t)k2 * 1024 + n]);
    sw2T[i] = f2bf(sw2[(size_t)k2 * 1024 + n]);
  }
  if (i < 16384) {
    int j = i >> 7, k = i & 127;                   // wT[j][k] = w[k][j]
    rw1T[i] = f2bf(rw1[k * 128 + j]);
    sw1T[i] = f2bf(sw1[k * 128 + j]);
    lw1T[i] = f2bf(lw1[k * 128 + j]);
  }
}

// ------------------------------------------------------------------
// kA: pre[row][j] = sum_d r_src[row][d] * lat_w1[d][j]   (no bias)
// MFMA 16x16x32 bf16. 1024 WGs x 256 thr; wave = 16 rows, N=128 full.
// A-frag: lane l holds A[l&15][(l>>4)*8 + j]  (verified m89 layout)
// B-frag: lane l holds B[(l>>4)*8 + j][l&15]
// C-frag: lane l holds C[(l>>4)*4 + r][l&15]
// ------------------------------------------------------------------
__global__ __launch_bounds__(256) void kA(const float* __restrict__ rsrc,
                                          const unsigned short* __restrict__ w1T,
                                          float* __restrict__ pre) {
  int w = threadIdx.x >> 6, l = threadIdx.x & 63;
  int m0 = blockIdx.x * 64 + w * 16;
  int rl = l & 15, kq = l >> 4;
  f32x4 acc[8] = {};
  const float* arow = rsrc + (size_t)(m0 + rl) * 1024 + kq * 8;
  for (int k0 = 0; k0 < 1024; k0 += 32) {
    float4 a01 = *(const float4*)(arow + k0);
    float4 a23 = *(const float4*)(arow + k0 + 4);
    bf16x8 af;
    af[0] = (short)f2bf(a01.x); af[1] = (short)f2bf(a01.y);
    af[2] = (short)f2bf(a01.z); af[3] = (short)f2bf(a01.w);
    af[4] = (short)f2bf(a23.x); af[5] = (short)f2bf(a23.y);
    af[6] = (short)f2bf(a23.z); af[7] = (short)f2bf(a23.w);
#pragma unroll
    for (int nt = 0; nt < 8; nt++) {
      bf16x8 bfr = *(const bf16x8*)(w1T + (size_t)(nt * 16 + rl) * 1024 + k0 + kq * 8);
      acc[nt] = __builtin_amdgcn_mfma_f32_16x16x32_bf16(af, bfr, acc[nt], 0, 0, 0);
    }
  }
#pragma unroll
  for (int nt = 0; nt < 8; nt++)
#pragma unroll
    for (int r = 0; r < 4; r++)
      pre[(size_t)(m0 + kq * 4 + r) * 128 + nt * 16 + rl] = acc[nt][r];
}

// ------------------------------------------------------------------
// kB: sequential scan. 32 WGs (one per batch) x 512 threads.
// Weights register-resident; activations broadcast via LDS; 5 barriers/step.
// wreg map: [0..63]  tid<128: lat_w1[1024+k][tid] ; tid in[128,320): gru_wh[k][tid-128]
//           [64..127] tid<192: gru_wi[k][tid]
//           [96..127] tid>=256: lat_w2[(q4*32+kk)][c]   (disjoint with wi users)
// ------------------------------------------------------------------
__global__ __launch_bounds__(512) void kB(
    const float* __restrict__ pre, const float* __restrict__ lat_w1,
    const float* __restrict__ lat_b1, const float* __restrict__ lat_w2,
    const float* __restrict__ lat_b2, const float* __restrict__ gwi,
    const float* __restrict__ gbi, const float* __restrict__ gwh,
    const float* __restrict__ gbh, unsigned short* __restrict__ feat) {
  __shared__ __align__(16) float hS[64];
  __shared__ __align__(16) float hidS[128];
  __shared__ __align__(16) float ghS[192];
  __shared__ __align__(16) float giS[192];
  __shared__ __align__(16) float partS[4][64];
  __shared__ __align__(16) float zS[64];
  const int tid = threadIdx.x;
  const int b = blockIdx.x;

  float wreg[128];
  if (tid < 128) {
#pragma unroll
    for (int k = 0; k < 64; k++) wreg[k] = lat_w1[(size_t)(1024 + k) * 128 + tid];
  } else if (tid < 320) {
#pragma unroll
    for (int k = 0; k < 64; k++) wreg[k] = gwh[k * 192 + (tid - 128)];
  }
  if (tid < 192) {
#pragma unroll
    for (int k = 0; k < 64; k++) wreg[64 + k] = gwi[k * 192 + tid];
  }
  if (tid >= 256) {
    int c = (tid - 256) & 63, q4 = (tid - 256) >> 6;
#pragma unroll
    for (int kk = 0; kk < 32; kk++) wreg[96 + kk] = lat_w2[(q4 * 32 + kk) * 64 + c];
  }
  float b1r = (tid < 128) ? lat_b1[tid] : 0.f;
  float bir = (tid < 192) ? gbi[tid] : 0.f;
  float bhr = (tid >= 128 && tid < 320) ? gbh[tid - 128] : 0.f;
  float b2r = (tid >= 448) ? lat_b2[tid - 448] : 0.f;
  if (tid < 64) hS[tid] = 0.f;
  __syncthreads();

  const float* prept = pre + (size_t)b * T_SZ * 128 + tid;  // valid for tid<128
  unsigned short* featp = feat + (size_t)b * T_SZ * 128;
  float pre_c = (tid < 128) ? prept[0] : 0.f;

  for (int t = 0; t < T_SZ; t++) {
    // prefetch next pre (latency hidden under this step)
    float pre_n = 0.f;
    if (tid < 128 && t + 1 < T_SZ) pre_n = prept[(size_t)(t + 1) * 128];

    // P1: hid = gelu(pre + b1 + h@w1h) ; gh = bh + h@wh
    if (tid < 320) {
      float acc = (tid < 128) ? (pre_c + b1r) : bhr;
      const float4* h4 = (const float4*)hS;
#pragma unroll
      for (int k4 = 0; k4 < 16; k4++) {
        float4 hv = h4[k4];
        acc += hv.x * wreg[4 * k4] + hv.y * wreg[4 * k4 + 1] +
               hv.z * wreg[4 * k4 + 2] + hv.w * wreg[4 * k4 + 3];
      }
      if (tid < 128) hidS[tid] = gelu_f(acc);
      else ghS[tid - 128] = acc;
    }
    __syncthreads();  // B1

    // P2: logits partials (K split by 4)
    if (tid >= 256) {
      int c = (tid - 256) & 63, q4 = (tid - 256) >> 6;
      const float4* hid4 = (const float4*)(hidS + q4 * 32);
      float acc = 0.f;
#pragma unroll
      for (int k4 = 0; k4 < 8; k4++) {
        float4 hv = hid4[k4];
        acc += hv.x * wreg[96 + 4 * k4] + hv.y * wreg[96 + 4 * k4 + 1] +
               hv.z * wreg[96 + 4 * k4 + 2] + hv.w * wreg[96 + 4 * k4 + 3];
      }
      partS[q4][c] = acc;
    }
    __syncthreads();  // B2

    // P2b: combine + softmax (wave 7, lane==c) + write z half of feat
    if (tid >= 448) {
      int c = tid - 448;
      float lg = partS[0][c] + partS[1][c] + partS[2][c] + partS[3][c] + b2r;
      float m = lg;
      m = fmaxf(m, __shfl_xor(m, 1, 64));
      m = fmaxf(m, __shfl_xor(m, 2, 64));
      m = fmaxf(m, __shfl_xor(m, 4, 64));
      float e = __expf(lg - m);
      float s = e;
      s += __shfl_xor(s, 1, 64);
      s += __shfl_xor(s, 2, 64);
      s += __shfl_xor(s, 4, 64);
      float z = e * __builtin_amdgcn_rcpf(s);
      zS[c] = z;
      featp[(size_t)t * 128 + c] = f2bf(z);
    }
    __syncthreads();  // B3

    // P3: gi = bi + z@wi
    if (tid < 192) {
      const float4* z4 = (const float4*)zS;
      float acc = bir;
#pragma unroll
      for (int k4 = 0; k4 < 16; k4++) {
        float4 zv = z4[k4];
        acc += zv.x * wreg[64 + 4 * k4] + zv.y * wreg[64 + 4 * k4 + 1] +
               zv.z * wreg[64 + 4 * k4 + 2] + zv.w * wreg[64 + 4 * k4 + 3];
      }
      giS[tid] = acc;
    }
    __syncthreads();  // B4

    // P4: GRU pointwise, h update, write h half of feat
    if (tid < 64) {
      float ir = giS[tid], iz = giS[tid + 64], inn = giS[tid + 128];
      float hr = ghS[tid], hz = ghS[tid + 64], hn = ghS[tid + 128];
      float hq = hS[tid];
      float r = 1.0f / (1.0f + __expf(-(ir + hr)));
      float u = 1.0f / (1.0f + __expf(-(iz + hz)));
      float n = tanhf(inn + r * hn);
      float hnew = (1.0f - u) * n + u * hq;
      hS[tid] = hnew;
      featp[(size_t)t * 128 + 64 + tid] = f2bf(hnew);
    }
    __syncthreads();  // B5
    pre_c = pre_n;
  }
}

// ------------------------------------------------------------------
// kC: heads. 1024 WGs x 256 thr; wave = 16 rows.
// head h: hidden = gelu(feat@w1+b1) -> LDS -> (h<2) out = hidden@w2+b2 ; h==2 loss dot
// ------------------------------------------------------------------
__global__ __launch_bounds__(256) void kC(
    const unsigned short* __restrict__ feat,
    const unsigned short* __restrict__ rw1T, const unsigned short* __restrict__ rw2T,
    const unsigned short* __restrict__ sw1T, const unsigned short* __restrict__ sw2T,
    const unsigned short* __restrict__ lw1T,
    const float* __restrict__ rb1, const float* __restrict__ rb2,
    const float* __restrict__ sb1, const float* __restrict__ sb2,
    const float* __restrict__ lb1, const float* __restrict__ lw2,
    const float* __restrict__ lb2,
    float* __restrict__ out_ss, float* __restrict__ out_r2,
    float* __restrict__ out_lh) {
  __shared__ unsigned short hidS[4][16][136];  // +8 pad: bank-conflict-free b128 reads
  __shared__ float w2l[128];
  int w = threadIdx.x >> 6, l = threadIdx.x & 63;
  if (threadIdx.x < 128) w2l[threadIdx.x] = lw2[threadIdx.x];
  int m0 = blockIdx.x * 64 + w * 16;
  int rl = l & 15, kq = l >> 4;

  bf16x8 af[4];
#pragma unroll
  for (int ks = 0; ks < 4; ks++)
    af[ks] = *(const bf16x8*)(feat + (size_t)(m0 + rl) * 128 + ks * 32 + kq * 8);

  const unsigned short* w1s[3] = {rw1T, sw1T, lw1T};
  const float* b1s[3] = {rb1, sb1, lb1};
  const unsigned short* w2s[2] = {rw2T, sw2T};
  const float* b2s[2] = {rb2, sb2};
  float* outs[2] = {out_r2, out_ss};

  for (int h = 0; h < 3; h++) {
    f32x4 acc1[8] = {};
#pragma unroll
    for (int ks = 0; ks < 4; ks++) {
#pragma unroll
      for (int nt = 0; nt < 8; nt++) {
        bf16x8 bfr = *(const bf16x8*)(w1s[h] + (size_t)(nt * 16 + rl) * 128 + ks * 32 + kq * 8);
        acc1[nt] = __builtin_amdgcn_mfma_f32_16x16x32_bf16(af[ks], bfr, acc1[nt], 0, 0, 0);
      }
    }
    __syncthreads();  // previous head done reading hidS
#pragma unroll
    for (int nt = 0; nt < 8; nt++) {
      float b1v = b1s[h][nt * 16 + rl];
#pragma unroll
      for (int r = 0; r < 4; r++) {
        float x = acc1[nt][r] + b1v;
        hidS[w][kq * 4 + r][nt * 16 + rl] = f2bf(gelu_f(x));
      }
    }
    __syncthreads();  // hidS (and w2l on first iter) visible

    if (h < 2) {
      bf16x8 ah[4];
#pragma unroll
      for (int ks = 0; ks < 4; ks++)
        ah[ks] = *(const bf16x8*)(&hidS[w][rl][ks * 32 + kq * 8]);
      float* outp = outs[h];
      for (int cb = 0; cb < 1024; cb += 256) {
        f32x4 acc2[16] = {};
#pragma unroll
        for (int ks = 0; ks < 4; ks++) {
#pragma unroll
          for (int nt = 0; nt < 16; nt++) {
            bf16x8 bfr = *(const bf16x8*)(w2s[h] + (size_t)(cb + nt * 16 + rl) * 128 + ks * 32 + kq * 8);
            acc2[nt] = __builtin_amdgcn_mfma_f32_16x16x32_bf16(ah[ks], bfr, acc2[nt], 0, 0, 0);
          }
        }
#pragma unroll
        for (int nt = 0; nt < 16; nt++) {
          float b2v = b2s[h][cb + nt * 16 + rl];
#pragma unroll
          for (int r = 0; r < 4; r++)
            outp[(size_t)(m0 + kq * 4 + r) * 1024 + cb + nt * 16 + rl] = acc2[nt][r] + b2v;
        }
      }
    } else {
      if (l < 16) {
        float sum = lb2[0];
        for (int c = 0; c < 128; c++) sum += bf2f(hidS[w][l][c]) * w2l[c];
        out_lh[m0 + l] = sum;
      }
    }
  }
}

// ------------------------------------------------------------------
extern "C" void kernel_launch(void* const* d_in, const int* in_sizes, int n_in,
                              void* d_out, int out_size, void* d_ws, size_t ws_size,
                              hipStream_t stream) {
  const float* r_src  = (const float*)d_in[0];
  const float* lat_w1 = (const float*)d_in[1];
  const float* lat_b1 = (const float*)d_in[2];
  const float* lat_w2 = (const float*)d_in[3];
  const float* lat_b2 = (const float*)d_in[4];
  const float* gwi    = (const float*)d_in[5];
  const float* gbi    = (const float*)d_in[6];
  const float* gwh    = (const float*)d_in[7];
  const float* gbh    = (const float*)d_in[8];
  const float* sw1    = (const float*)d_in[9];
  const float* sb1    = (const float*)d_in[10];
  const float* sw2    = (const float*)d_in[11];
  const float* sb2    = (const float*)d_in[12];
  const float* rw1    = (const float*)d_in[13];
  const float* rb1    = (const float*)d_in[14];
  const float* rw2    = (const float*)d_in[15];
  const float* rb2    = (const float*)d_in[16];
  const float* lw1    = (const float*)d_in[17];
  const float* lb1    = (const float*)d_in[18];
  const float* lw2    = (const float*)d_in[19];
  const float* lb2    = (const float*)d_in[20];

  char* wsb = (char*)d_ws;
  float* pre           = (float*)(wsb);                       // 32 MiB
  unsigned short* feat = (unsigned short*)(wsb + 33554432);   // 16 MiB
  unsigned short* w1T  = (unsigned short*)(wsb + 50331648);   // 256 KiB
  unsigned short* rw1T = (unsigned short*)(wsb + 50593792);   // 32 KiB
  unsigned short* sw1T = (unsigned short*)(wsb + 50626560);   // 32 KiB
  unsigned short* lw1T = (unsigned short*)(wsb + 50659328);   // 32 KiB
  unsigned short* rw2T = (unsigned short*)(wsb + 50692096);   // 256 KiB
  unsigned short* sw2T = (unsigned short*)(wsb + 50954240);   // 256 KiB

  float* out_ss = (float*)d_out;                 // (B,T,1024)
  float* out_r2 = out_ss + (size_t)NROW * 1024;  // (B,T,1024)
  float* out_lh = out_r2 + (size_t)NROW * 1024;  // (B,T)

  hipLaunchKernelGGL(kPrep, dim3(512), dim3(256), 0, stream,
                     lat_w1, rw1, rw2, sw1, sw2, lw1, w1T, rw1T, rw2T, sw1T, sw2T, lw1T);
  hipLaunchKernelGGL(kA, dim3(1024), dim3(256), 0, stream, r_src, w1T, pre);
  hipLaunchKernelGGL(kB, dim3(32), dim3(512), 0, stream,
                     pre, lat_w1, lat_b1, lat_w2, lat_b2, gwi, gbi, gwh, gbh, feat);
  hipLaunchKernelGGL(kC, dim3(1024), dim3(256), 0, stream,
                     feat, rw1T, rw2T, sw1T, sw2T, lw1T,
                     rb1, rb2, sb1, sb2, lb1, lw2, lb2, out_ss, out_r2, out_lh);
}